// Round 7
// baseline (267.299 us; speedup 1.0000x reference)
//
#include <hip/hip_runtime.h>

#define B_ 4
#define C_ 512
#define H_ 64
#define W_ 208
#define HID_ 512
#define NREG_ 4
#define DS_ 16

typedef float f32x4 __attribute__((ext_vector_type(4)));
typedef int i32x4 __attribute__((ext_vector_type(4)));

// ws layout: tmp [B*NREG*HID_] fp32 @0 (32KB) | delta [B*NREG*C_] fp32 @32KB | swl [B*W_] int @64KB
// No memset: tmp, delta, swl fully overwritten every launch (no atomics anywhere).

// prep1: blocks 0..63  : tmp[b,r,d0+dd] = sum_h tf[r,b,h]*Wv[r,h,d0+dd]
//        blocks 64..67 : parallel stable counting sort of column labels, b = blk-64.
__global__ __launch_bounds__(256) void prep1_kernel(
    const float* __restrict__ tf, const float* __restrict__ Wv,
    const int* __restrict__ mask, float* __restrict__ tmp, int* __restrict__ swl) {
  int blk = blockIdx.x, tid = threadIdx.x;
  if (blk < 64) {
    int r = blk >> 4;
    int d0 = (blk & 15) * 32;
    __shared__ float tf_s[B_ * HID_];
    __shared__ float red[8][B_][32];
#pragma unroll
    for (int k = 0; k < 8; ++k) {
      int idx = k * 256 + tid;
      tf_s[idx] = tf[r * (B_ * HID_) + idx];
    }
    __syncthreads();
    int hg = tid >> 5, dd = tid & 31;
    float acc[B_] = {};
#pragma unroll 4
    for (int q = 0; q < 64; ++q) {
      int hh = hg * 64 + q;
      float w = Wv[(size_t)(r * HID_ + hh) * HID_ + d0 + dd];
#pragma unroll
      for (int b = 0; b < B_; ++b) acc[b] += tf_s[b * HID_ + hh] * w;
    }
#pragma unroll
    for (int b = 0; b < B_; ++b) red[hg][b][dd] = acc[b];
    __syncthreads();
    if (tid < 128) {
      int b2 = tid >> 5, d2 = tid & 31;
      float s = 0.f;
#pragma unroll
      for (int q = 0; q < 8; ++q) s += red[q][b2][d2];
      tmp[(b2 * NREG_ + r) * HID_ + d0 + d2] = s;
    }
  } else {
    int b = blk - 64;
    const size_t mb = (size_t)b * (H_ * DS_) * (W_ * DS_);
    int w = tid;
    int l = (w < W_) ? (mask[mb + (size_t)w * DS_] - 1) : -1;
    int wave = tid >> 6, lane = tid & 63;
    unsigned long long bal[NREG_];
    __shared__ int wcnt[4][NREG_];
#pragma unroll
    for (int r = 0; r < NREG_; ++r) bal[r] = __ballot(l == r);
    if (lane < NREG_) wcnt[wave][lane] = __popcll(bal[lane]);
    __syncthreads();
    if (w < W_) {
      int pos = 0;
#pragma unroll
      for (int q = 0; q < NREG_; ++q) {
        int tot = wcnt[0][q] + wcnt[1][q] + wcnt[2][q] + wcnt[3][q];
        if (q < l) pos += tot;
      }
#pragma unroll
      for (int v = 0; v < 4; ++v)
        if (v < wave) pos += wcnt[v][l];
      pos += __popcll(bal[l] & ((1ull << lane) - 1ull));
      swl[b * W_ + pos] = w | (l << 16);
    }
  }
}

// prep2: delta[b,r,c0+cc] = sum_d tmp[b,r,d]*Wo[r,d,c0+cc]; 32 blocks.
__global__ __launch_bounds__(256) void prep2_kernel(
    const float* __restrict__ tmp, const float* __restrict__ Wo,
    float* __restrict__ delta) {
  int blk = blockIdx.x, tid = threadIdx.x;
  int r = blk >> 3;
  int c0 = (blk & 7) * 64;
  __shared__ float tmp_s[B_ * HID_];
  __shared__ float red[4][B_][64];
#pragma unroll
  for (int k = 0; k < 8; ++k) {
    int idx = k * 256 + tid;
    int b = idx >> 9, d = idx & 511;
    tmp_s[idx] = tmp[(b * NREG_ + r) * HID_ + d];
  }
  __syncthreads();
  int dg = tid >> 6, cc = tid & 63;
  float acc[B_] = {};
#pragma unroll 4
  for (int q = 0; q < 128; ++q) {
    int d = dg * 128 + q;
    float w = Wo[(size_t)(r * HID_ + d) * C_ + c0 + cc];
#pragma unroll
    for (int b = 0; b < B_; ++b) acc[b] += tmp_s[b * HID_ + d] * w;
  }
#pragma unroll
  for (int b = 0; b < B_; ++b) red[dg][b][cc] = acc[b];
  __syncthreads();
  {  // dg slot reused as b
    float s = red[0][dg][cc] + red[1][dg][cc] + red[2][dg][cc] + red[3][dg][cc];
    delta[(dg * NREG_ + r) * C_ + c0 + cc] = s;
  }
}

// apply v6: PERSISTENT PIPELINED WAVES.
// Round-5 post-mortem: traffic is minimal (53+106 MB) but apply sits at 2.5 TB/s
// while fillBuffer does 6.5 and round-3's spill-heavy version sustained 3.6 —
// the limiter is read-issue duty cycle (load burst -> drain -> long gather with
// no loads in flight), not bandwidth. Fix: one wave per block (64 thr, grid
// 1024, 4 blocks/CU @ 28.3KB LDS), each wave owns 2 consecutive planes = 8
// 16-row tile-units, DOUBLE-BUFFERED: drain vmcnt(0) -> immediately issue next
// unit's 13 global_load_lds into the other buffer -> gather/store current unit
// while they fly. Load latency hidden under the previous gather for 7/8 units.
// Zero barriers; tables wave-private; both planes' dsel prefetched to regs so
// the mid-stream dquad refresh is register+LDS only (no vmcnt-draining load).
#define RCH_ (W_ / 4)                 // 52 float4 per row
__device__ __forceinline__ void gload_lds16(const float* g, float* l) {
  __builtin_amdgcn_global_load_lds(
      (const __attribute__((address_space(1))) void*)g,
      (__attribute__((address_space(3))) void*)l, 16, 0, 0);
}
__global__ __launch_bounds__(64) void apply_kernel(
    const float* __restrict__ img, const float* __restrict__ delta,
    const int* __restrict__ swl, float* __restrict__ out) {
  int lane = threadIdx.x;
  int gw = blockIdx.x;                  // 0..1023: one wave, two planes
  int p0 = gw * 2;
  int b = p0 >> 9;                      // both planes share b (p0 even)
  int c0 = p0 & (C_ - 1);
  __shared__ float tile[2][16 * W_];    // 2 x 13312 B double buffer
  __shared__ int swl_s[W_];             // swl_s[pos] = src_col | (label<<16)
  __shared__ float dq_s[W_];            // delta per OUTPUT position (current plane)

  if (lane < 52) ((i32x4*)swl_s)[lane] = ((const i32x4*)(swl + b * W_))[lane];

  // dsel for BOTH planes -> registers (avoids any global load in the loop)
  float v0 = 0.f, v1 = 0.f;
  if (lane < NREG_) {
    v0 = delta[(b * NREG_ + lane) * C_ + c0];
    v1 = delta[(b * NREG_ + lane) * C_ + c0 + 1];
  }
  float e0 = __shfl(v0, 0), e1 = __shfl(v0, 1), e2 = __shfl(v0, 2), e3 = __shfl(v0, 3);
  float f0 = __shfl(v1, 0), f1 = __shfl(v1, 1), f2 = __shfl(v1, 2), f3 = __shfl(v1, 3);
  // dquad for plane 0 (needs swl_s: compiler inserts the vmcnt/lgkm waits)
#pragma unroll
  for (int q = 0; q < 4; ++q) {
    int pos = q * 64 + lane;
    if (pos < W_) {
      int lab = swl_s[pos] >> 16;
      dq_s[pos] = lab == 0 ? e0 : lab == 1 ? e1 : lab == 2 ? e2 : e3;
    }
  }

  // stage unit 0
  {
    const float* src = img + (size_t)p0 * (H_ * W_);
#pragma unroll
    for (int k = 0; k < 13; ++k)
      gload_lds16(src + (k * 64 + lane) * 4, &tile[0][k * 256]);
  }
  int cur = 0;
  const i32x4* swl4 = (const i32x4*)swl_s;
  const f32x4* dq4 = (const f32x4*)dq_s;
  for (int u = 0; u < 8; ++u) {
    // drain unit u's loads (+ previous stores); next unit's loads not yet issued
    asm volatile("s_waitcnt vmcnt(0)" ::: "memory");
    if (u < 7) {
      int un = u + 1;
      const float* srcn =
          img + ((size_t)(p0 + (un >> 2)) * H_ + (un & 3) * 16) * W_;
      float* nb = tile[cur ^ 1];
#pragma unroll
      for (int k = 0; k < 13; ++k)
        gload_lds16(srcn + (k * 64 + lane) * 4, &nb[k * 256]);
    }
    // gather unit u from LDS, coalesced NT stores (overlaps next unit's loads)
    int p = p0 + (u >> 2), qr = u & 3;
    f32x4* dstv = (f32x4*)out + ((size_t)p * (H_ * RCH_) + qr * (16 * RCH_));
    const float* mytile = tile[cur];
#pragma unroll
    for (int k = 0; k < 13; ++k) {
      int i = k * 64 + lane;
      int hl = i / RCH_;
      int jo = i - hl * RCH_;
      i32x4 sw = swl4[jo];
      f32x4 dq = dq4[jo];
      const float* rowp = mytile + hl * W_;
      f32x4 o;
      o.x = rowp[sw.x & 0xFFFF] + dq.x;
      o.y = rowp[sw.y & 0xFFFF] + dq.y;
      o.z = rowp[sw.z & 0xFFFF] + dq.z;
      o.w = rowp[sw.w & 0xFFFF] + dq.w;
      __builtin_nontemporal_store(o, &dstv[i]);
    }
    if (u == 3) {  // switch dquad to plane 1 (register-only sources; same-wave
                   // DS ordering keeps these writes after the u=3 gather reads)
#pragma unroll
      for (int q = 0; q < 4; ++q) {
        int pos = q * 64 + lane;
        if (pos < W_) {
          int lab = swl_s[pos] >> 16;
          dq_s[pos] = lab == 0 ? f0 : lab == 1 ? f1 : lab == 2 ? f2 : f3;
        }
      }
    }
    cur ^= 1;
  }
}

extern "C" void kernel_launch(void* const* d_in, const int* in_sizes, int n_in,
                              void* d_out, int out_size, void* d_ws, size_t ws_size,
                              hipStream_t stream) {
  const float* img  = (const float*)d_in[0];   // image_feature (B,C,H,W) fp32
  const float* tf   = (const float*)d_in[1];   // text_feat (NREG,B,HID) fp32
  const int*   mask = (const int*)d_in[2];     // text_mask (B,1,H*DS,W*DS) int32
  // d_in[3] = Wq (unused), d_in[4] = Wk (unused)
  const float* Wv   = (const float*)d_in[5];   // (NREG,HID,HID) fp32
  const float* Wo   = (const float*)d_in[6];   // (NREG,HID,C) fp32
  float* tmp   = (float*)d_ws;
  float* delta = (float*)((char*)d_ws + 32768);
  int*   swl   = (int*)((char*)d_ws + 65536);
  float* out   = (float*)d_out;

  prep1_kernel<<<68, 256, 0, stream>>>(tf, Wv, mask, tmp, swl);
  prep2_kernel<<<32, 256, 0, stream>>>(tmp, Wo, delta);
  apply_kernel<<<1024, 64, 0, stream>>>(img, delta, swl, out);
}

// Round 8
// 246.704 us; speedup vs baseline: 1.0835x; 1.0835x over previous
//
#include <hip/hip_runtime.h>

#define B_ 4
#define C_ 512
#define H_ 64
#define W_ 208
#define HID_ 512
#define NREG_ 4
#define DS_ 16

typedef float f32x4 __attribute__((ext_vector_type(4)));
typedef int i32x4 __attribute__((ext_vector_type(4)));

// ws layout: delta [B*NREG*C_] fp32 @0 (32KB) | tmp [B*NREG*HID_] fp32 @32KB | swl [B*W] int @64KB
// Wide prep kernels (reverted to round-0 form): non-apply time measured 171 µs
// with these vs 196 µs with the narrow 68/32-block no-atomic versions.

// Blocks 0..255: partial tmp[b,r,d] += sum_{h in 16-chunk} tf[r,b,h]*Wv[r,h,d]
// Blocks 256..259: parallel stable counting sort of column labels for b = blk-256
__global__ __launch_bounds__(256) void prepA_kernel(
    const float* __restrict__ tf, const float* __restrict__ Wv,
    const int* __restrict__ mask, float* __restrict__ tmp, int* __restrict__ swl) {
  int blk = blockIdx.x, tid = threadIdx.x;
  if (blk < 256) {
    int r = blk >> 6;
    int h0 = ((blk >> 3) & 7) * 64;
    int d0 = (blk & 7) * 64;
    int g = tid >> 6, dd = tid & 63;
    __shared__ float tf_s[B_][64];
    __shared__ float red[4][B_][64];
    tf_s[g][dd] = tf[(r * B_ + g) * HID_ + h0 + dd];  // g as b, dd as hh
    __syncthreads();
    float acc[B_] = {};
    for (int hh = g * 16; hh < g * 16 + 16; ++hh) {
      float w = Wv[(size_t)(r * HID_ + h0 + hh) * HID_ + d0 + dd];
#pragma unroll
      for (int b = 0; b < B_; ++b) acc[b] += tf_s[b][hh] * w;
    }
#pragma unroll
    for (int b = 0; b < B_; ++b) red[g][b][dd] = acc[b];
    __syncthreads();
    {  // g now indexes b
      float s = red[0][g][dd] + red[1][g][dd] + red[2][g][dd] + red[3][g][dd];
      atomicAdd(&tmp[(g * NREG_ + r) * HID_ + d0 + dd], s);
    }
  } else {
    int b = blk - 256;
    const size_t mb = (size_t)b * (H_ * DS_) * (W_ * DS_);
    int w = tid;
    int l = (w < W_) ? (mask[mb + (size_t)w * DS_] - 1) : -1;
    int wave = tid >> 6, lane = tid & 63;
    unsigned long long bal[NREG_];
    __shared__ int wcnt[4][NREG_];
#pragma unroll
    for (int r = 0; r < NREG_; ++r) bal[r] = __ballot(l == r);
    if (lane < NREG_) wcnt[wave][lane] = __popcll(bal[lane]);
    __syncthreads();
    if (w < W_) {
      int pos = 0;
#pragma unroll
      for (int q = 0; q < NREG_; ++q) {
        int tot = wcnt[0][q] + wcnt[1][q] + wcnt[2][q] + wcnt[3][q];
        if (q < l) pos += tot;
      }
#pragma unroll
      for (int v = 0; v < 4; ++v)
        if (v < wave) pos += wcnt[v][l];
      pos += __popcll(bal[l] & ((1ull << lane) - 1ull));
      swl[b * W_ + pos] = w | (l << 16);
    }
  }
}

// delta[b,r,c] += sum_{d in 16-chunk} tmp[b,r,d]*Wo[r,d,c]; same decomp as prepA
__global__ __launch_bounds__(256) void prepB_kernel(
    const float* __restrict__ tmp, const float* __restrict__ Wo,
    float* __restrict__ delta) {
  int blk = blockIdx.x, tid = threadIdx.x;
  int r = blk >> 6;
  int d0 = ((blk >> 3) & 7) * 64;
  int c0 = (blk & 7) * 64;
  int g = tid >> 6, cc = tid & 63;
  __shared__ float tmp_s[B_][64];
  __shared__ float red[4][B_][64];
  tmp_s[g][cc] = tmp[(g * NREG_ + r) * HID_ + d0 + cc];  // g as b, cc as dd
  __syncthreads();
  float acc[B_] = {};
  for (int dd = g * 16; dd < g * 16 + 16; ++dd) {
    float w = Wo[(size_t)(r * HID_ + d0 + dd) * C_ + c0 + cc];
#pragma unroll
    for (int b = 0; b < B_; ++b) acc[b] += tmp_s[b][dd] * w;
  }
#pragma unroll
  for (int b = 0; b < B_; ++b) red[g][b][cc] = acc[b];
  __syncthreads();
  {  // g now indexes b
    float s = red[0][g][cc] + red[1][g][cc] + red[2][g][cc] + red[3][g][cc];
    atomicAdd(&delta[(g * NREG_ + r) * C_ + c0 + cc], s);
  }
}

// apply v8: ROLLING COUNTED-VMCNT PIPELINE, one wave per (b,c) plane.
// Post-mortems: r5's vmcnt(0) and r7's loop-top vmcnt(0) both wait on the NT
// STORES issued in between (vmcnt retires in issue order) -> every wave's
// critical path includes a store round-trip, and the read stream idles. Here
// the waits are exact in-order-retire counts that cover ONLY the loads of the
// unit about to be gathered; stores are never waited on inside the kernel
// (they drain at wave end). Unit u+1's 13 loads are always in flight during
// unit u's gather. Issue-order ledger (after prologue drain):
//   L0:0-12  L1:13-25  S0:26-38  L2:39-51  S1:52-64  L3:65-77  S2:78-90  S3:...
//   unit0: issued 26, need pos<=12  -> vmcnt(13)
//   unit1: issued 52, need pos<=25  -> vmcnt(26)
//   unit2: issued 78, need pos<=51  -> vmcnt(26)
//   unit3: issued 91, need pos<=77  -> vmcnt(13)
// LDS 28.3 KB -> 5 blocks/CU; ~26 VMEM in flight/wave, ~130/CU.
#define RCH_ (W_ / 4)                 // 52 float4 per row
__device__ __forceinline__ void gload_lds16(const float* g, float* l) {
  __builtin_amdgcn_global_load_lds(
      (const __attribute__((address_space(1))) void*)g,
      (__attribute__((address_space(3))) void*)l, 16, 0, 0);
}
__global__ __launch_bounds__(64) void apply_kernel(
    const float* __restrict__ img, const float* __restrict__ delta,
    const int* __restrict__ swl, float* __restrict__ out) {
  int lane = threadIdx.x;
  int p = blockIdx.x;                   // plane = (b,c)
  int b = p >> 9;
  int c = p & (C_ - 1);
  __shared__ float tile[2][16 * W_];    // 2 x 13312 B double buffer
  __shared__ int swl_s[W_];             // swl_s[pos] = src_col | (label<<16)
  __shared__ float dq_s[W_];            // delta per OUTPUT position

  if (lane < 52) ((i32x4*)swl_s)[lane] = ((const i32x4*)(swl + b * W_))[lane];
  float v0 = 0.f;
  if (lane < NREG_) v0 = delta[(b * NREG_ + lane) * C_ + c];
  float e0 = __shfl(v0, 0), e1 = __shfl(v0, 1), e2 = __shfl(v0, 2), e3 = __shfl(v0, 3);
#pragma unroll
  for (int q = 0; q < 4; ++q) {
    int pos = q * 64 + lane;
    if (pos < W_) {
      int lab = swl_s[pos] >> 16;
      dq_s[pos] = lab == 0 ? e0 : lab == 1 ? e1 : lab == 2 ? e2 : e3;
    }
  }
  const float* src = img + (size_t)p * (H_ * W_);
  f32x4* dstv = (f32x4*)out + (size_t)p * (H_ * RCH_);

  // Baseline: drain the 2 prologue table loads so the ledger starts at 0.
  asm volatile("s_waitcnt vmcnt(0)" ::: "memory");
  // Issue units 0 and 1 (26 loads in flight).
#pragma unroll
  for (int k = 0; k < 13; ++k)
    gload_lds16(src + (k * 64 + lane) * 4, &tile[0][k * 256]);
#pragma unroll
  for (int k = 0; k < 13; ++k)
    gload_lds16(src + 16 * W_ + (k * 64 + lane) * 4, &tile[1][k * 256]);

  const i32x4* swl4 = (const i32x4*)swl_s;
  const f32x4* dq4 = (const f32x4*)dq_s;
  auto gather_unit = [&](int u) {
    const float* mytile = tile[u & 1];
    f32x4* du = dstv + u * (16 * RCH_);
#pragma unroll
    for (int k = 0; k < 13; ++k) {
      int i = k * 64 + lane;
      int hl = i / RCH_;
      int jo = i - hl * RCH_;
      i32x4 sw = swl4[jo];
      f32x4 dq = dq4[jo];
      const float* rowp = mytile + hl * W_;
      f32x4 o;
      o.x = rowp[sw.x & 0xFFFF] + dq.x;
      o.y = rowp[sw.y & 0xFFFF] + dq.y;
      o.z = rowp[sw.z & 0xFFFF] + dq.z;
      o.w = rowp[sw.w & 0xFFFF] + dq.w;
      __builtin_nontemporal_store(o, &du[i]);
    }
  };

  asm volatile("s_waitcnt vmcnt(13)" ::: "memory");   // unit0 loads done
  gather_unit(0);
  asm volatile("s_waitcnt lgkmcnt(0)" ::: "memory");  // buf0 reads done
#pragma unroll
  for (int k = 0; k < 13; ++k)
    gload_lds16(src + 2 * 16 * W_ + (k * 64 + lane) * 4, &tile[0][k * 256]);
  asm volatile("s_waitcnt vmcnt(26)" ::: "memory");   // unit1 loads done
  gather_unit(1);
  asm volatile("s_waitcnt lgkmcnt(0)" ::: "memory");  // buf1 reads done
#pragma unroll
  for (int k = 0; k < 13; ++k)
    gload_lds16(src + 3 * 16 * W_ + (k * 64 + lane) * 4, &tile[1][k * 256]);
  asm volatile("s_waitcnt vmcnt(26)" ::: "memory");   // unit2 loads done
  gather_unit(2);
  asm volatile("s_waitcnt vmcnt(13)" ::: "memory");   // unit3 loads done
  gather_unit(3);
  // stores drain implicitly at wave end
}

extern "C" void kernel_launch(void* const* d_in, const int* in_sizes, int n_in,
                              void* d_out, int out_size, void* d_ws, size_t ws_size,
                              hipStream_t stream) {
  const float* img  = (const float*)d_in[0];   // image_feature (B,C,H,W) fp32
  const float* tf   = (const float*)d_in[1];   // text_feat (NREG,B,HID) fp32
  const int*   mask = (const int*)d_in[2];     // text_mask (B,1,H*DS,W*DS) int32
  // d_in[3] = Wq (unused), d_in[4] = Wk (unused)
  const float* Wv   = (const float*)d_in[5];   // (NREG,HID,HID) fp32
  const float* Wo   = (const float*)d_in[6];   // (NREG,HID,C) fp32
  float* delta = (float*)d_ws;
  float* tmp   = (float*)((char*)d_ws + 32768);
  int*   swl   = (int*)((char*)d_ws + 65536);
  float* out   = (float*)d_out;

  hipMemsetAsync(d_ws, 0, 65536, stream);  // zero delta + tmp (atomic accumulators)
  prepA_kernel<<<260, 256, 0, stream>>>(tf, Wv, mask, tmp, swl);
  prepB_kernel<<<256, 256, 0, stream>>>(tmp, Wo, delta);
  apply_kernel<<<B_ * C_, 64, 0, stream>>>(img, delta, swl, out);
}